// Round 19
// baseline (90.803 us; speedup 1.0000x reference)
//
#include <hip/hip_runtime.h>

// EKF_v2: B=16384, N=128, DX=5, DZ=2.
// R18 + ONE change: layer-2/3 weights moved OFF the DS pipe. Diagnosis:
// ~170 of ~275 DS-pipe ops/wave were the s_wt LDS table reads; DS-pipe
// arithmetic (~2600cyc/wave x 64 waves/CU = ~69us) matches observed dur.
// Weights now read directly from global with wave-uniform indices ->
// s_load via K$ (SMEM pipe, idle). j-loop chunked 8x4 so per-k slices are
// contiguous s_load_dwordx4; acc[4] packed pairs keep VGPR <= 64.
// Same arithmetic order -> bit-identical absmax. No MFMA, no d_ws.

#define NBPB 4  // batches (=waves) per block

typedef float v2f __attribute__((ext_vector_type(2)));
__device__ __forceinline__ v2f spl(float x) { v2f r; r.x = x; r.y = x; return r; }

__global__ __launch_bounds__(256) void ekf_fused(
    const float* __restrict__ state_old,  // (B,128,5)
    const float* __restrict__ y_obs,      // (B,128,2)
    const float* __restrict__ encoding,   // (B,128)
    const float* __restrict__ pw1,        // (2,16)
    const float* __restrict__ pb1,        // (16)
    const float* __restrict__ pw2,        // (16,32)
    const float* __restrict__ pb2,        // (32)
    const float* __restrict__ pw3,        // (32,2)
    const float* __restrict__ pb3,        // (2)
    const float* __restrict__ nw1,        // (128,32)
    const float* __restrict__ nb1,        // (32)
    const float* __restrict__ nw2,        // (32,2)
    const float* __restrict__ nb2,        // (2)
    const float* __restrict__ lob,        // (2)
    const float* __restrict__ fob,        // (2)
    float* __restrict__ out)              // (B,128,5)
{
    __shared__ __align__(16) float s_state[NBPB * 640];

    const int t = threadIdx.x;
    const int base = blockIdx.x * NBPB;

    // ---- stage state (coalesced float4) ----
    {
        const float4* src = (const float4*)(state_old + (size_t)base * 640);
        float4* dst = (float4*)s_state;
        #pragma unroll
        for (int i = t; i < NBPB * 160; i += 256) dst[i] = src[i];
    }
    __syncthreads();

    const int w = t >> 6;    // wave = batch within block
    const int l = t & 63;
    const int c = l & 31;    // particle column
    const int h = l >> 5;    // lane half -> k-split & particle ownership
    const size_t b = (size_t)base + w;

    // ---- noise MLP: j = c, k-range split across halves ----
    float diag0, diag1;
    {
        const float4* eg4 = (const float4*)(encoding + b * 128) + h * 16;
        const float* wp = nw1 + (size_t)(h * 64) * 32 + c;
        float a0 = 0.f, a1 = 0.f, a2 = 0.f, a3 = 0.f;
        #pragma unroll
        for (int kk = 0; kk < 16; ++kk) {
            float4 e4 = eg4[kk];
            a0 = fmaf(e4.x, wp[(4 * kk + 0) * 32], a0);
            a1 = fmaf(e4.y, wp[(4 * kk + 1) * 32], a1);
            a2 = fmaf(e4.z, wp[(4 * kk + 2) * 32], a2);
            a3 = fmaf(e4.w, wp[(4 * kk + 3) * 32], a3);
        }
        float acc = (a0 + a1) + (a2 + a3);
        acc += __shfl_xor(acc, 32, 64);   // combine k-halves
        acc += nb1[c];
        float hh = fmaxf(acc, 0.f);
        float d0 = hh * nw2[2 * c + 0];
        float d1 = hh * nw2[2 * c + 1];
        #pragma unroll
        for (int off = 1; off < 32; off <<= 1) {
            d0 += __shfl_xor(d0, off, 64);
            d1 += __shfl_xor(d1, off, 64);
        }
        float e0 = d0 + nb2[0] + lob[0];
        float e1 = d1 + nb2[1] + lob[1];
        diag0 = fmaf(e0, e0, fob[0]);
        diag1 = fmaf(e1, e1, fob[1]);
    }

    const float* sp = s_state + w * 640;
    const int p0 = c + 32 * (2 * h);
    const int p1 = c + 32 * (2 * h + 1);

    // ---- process model pose for the 2 owned particles ----
    float xpo[2][5];
    float va, tda, vb, tdb;
    {
        const float* s5a = sp + p0 * 5;
        const float* s5b = sp + p1 * 5;
        va = s5a[3]; tda = s5a[4];
        vb = s5b[3]; tdb = s5b[4];
        float tha = s5a[2] + tda;
        float thb = s5b[2] + tdb;
        xpo[0][0] = fmaf(va, __sinf(tha), s5a[0]);
        xpo[0][1] = fmaf(va, __cosf(tha), s5a[1]);
        xpo[0][2] = tha;
        xpo[1][0] = fmaf(vb, __sinf(thb), s5b[0]);
        xpo[1][1] = fmaf(vb, __cosf(thb), s5b[1]);
        xpo[1][2] = thb;
    }

    // ---- layer-1 packed: h1p[q] = (h1a[q], h1b[q]); pw1/pb1 via s_load ----
    v2f h1p[16];
    {
        v2f vv;  vv.x = va;  vv.y = vb;
        v2f tdv; tdv.x = tda; tdv.y = tdb;
        #pragma unroll
        for (int q = 0; q < 16; ++q) {
            v2f tmp = __builtin_elementwise_fma(tdv, spl(pw1[16 + q]), spl(pb1[q]));
            v2f hq  = __builtin_elementwise_fma(vv, spl(pw1[q]), tmp);
            h1p[q] = __builtin_elementwise_max(hq, spl(0.0f));
        }
    }

    // ---- layers 2+3: weights via UNIFORM global reads (s_load / K$) ----
    // 8 chunks x 4 j; per k, pw2[k][j0..j0+3] is contiguous (s_load_dwordx4).
    v2f o3p = spl(0.0f), o4p = spl(0.0f);
    #pragma unroll
    for (int ch = 0; ch < 8; ++ch) {
        const int j0 = ch * 4;
        v2f acc0 = spl(pb2[j0 + 0]);
        v2f acc1 = spl(pb2[j0 + 1]);
        v2f acc2 = spl(pb2[j0 + 2]);
        v2f acc3 = spl(pb2[j0 + 3]);
        #pragma unroll
        for (int k = 0; k < 16; ++k) {
            const float* row = pw2 + k * 32 + j0;  // uniform -> s_load_dwordx4
            acc0 = __builtin_elementwise_fma(h1p[k], spl(row[0]), acc0);
            acc1 = __builtin_elementwise_fma(h1p[k], spl(row[1]), acc1);
            acc2 = __builtin_elementwise_fma(h1p[k], spl(row[2]), acc2);
            acc3 = __builtin_elementwise_fma(h1p[k], spl(row[3]), acc3);
        }
        v2f r0 = __builtin_elementwise_max(acc0, spl(0.0f));
        v2f r1 = __builtin_elementwise_max(acc1, spl(0.0f));
        v2f r2 = __builtin_elementwise_max(acc2, spl(0.0f));
        v2f r3 = __builtin_elementwise_max(acc3, spl(0.0f));
        o3p = __builtin_elementwise_fma(r0, spl(pw3[2 * (j0 + 0)]), o3p);
        o4p = __builtin_elementwise_fma(r0, spl(pw3[2 * (j0 + 0) + 1]), o4p);
        o3p = __builtin_elementwise_fma(r1, spl(pw3[2 * (j0 + 1)]), o3p);
        o4p = __builtin_elementwise_fma(r1, spl(pw3[2 * (j0 + 1) + 1]), o4p);
        o3p = __builtin_elementwise_fma(r2, spl(pw3[2 * (j0 + 2)]), o3p);
        o4p = __builtin_elementwise_fma(r2, spl(pw3[2 * (j0 + 2) + 1]), o4p);
        o3p = __builtin_elementwise_fma(r3, spl(pw3[2 * (j0 + 3)]), o3p);
        o4p = __builtin_elementwise_fma(r3, spl(pw3[2 * (j0 + 3) + 1]), o4p);
    }
    {
        float pb30 = pb3[0], pb31 = pb3[1];
        xpo[0][3] = va + o3p.x + pb30;
        xpo[0][4] = tda + o4p.x + pb31;
        xpo[1][3] = vb + o3p.y + pb30;
        xpo[1][4] = tdb + o4p.y + pb31;
    }

    // ---- raw moments: ONE butterfly phase (6 levels), 14 chains ----
    float red[14];
    #pragma unroll
    for (int i = 0; i < 5; ++i) red[i] = xpo[0][i] + xpo[1][i];
    red[5]  = xpo[0][0] * xpo[0][3] + xpo[1][0] * xpo[1][3];
    red[6]  = xpo[0][0] * xpo[0][4] + xpo[1][0] * xpo[1][4];
    red[7]  = xpo[0][1] * xpo[0][3] + xpo[1][1] * xpo[1][3];
    red[8]  = xpo[0][1] * xpo[0][4] + xpo[1][1] * xpo[1][4];
    red[9]  = xpo[0][2] * xpo[0][3] + xpo[1][2] * xpo[1][3];
    red[10] = xpo[0][2] * xpo[0][4] + xpo[1][2] * xpo[1][4];
    red[11] = xpo[0][3] * xpo[0][3] + xpo[1][3] * xpo[1][3];
    red[12] = xpo[0][3] * xpo[0][4] + xpo[1][3] * xpo[1][4];
    red[13] = xpo[0][4] * xpo[0][4] + xpo[1][4] * xpo[1][4];
    #pragma unroll
    for (int off = 1; off < 64; off <<= 1) {
        #pragma unroll
        for (int r = 0; r < 14; ++r)
            red[r] += __shfl_xor(red[r], off, 64);
    }

    // ---- covariances + analytic 2x2 solve ----
    const float inv  = 1.0f / 127.0f;
    const float minv = inv * 0.0078125f; // 1/(127*128)
    float S00 = red[5]  * inv - red[0] * red[3] * minv;
    float S01 = red[6]  * inv - red[0] * red[4] * minv;
    float S10 = red[7]  * inv - red[1] * red[3] * minv;
    float S11 = red[8]  * inv - red[1] * red[4] * minv;
    float S20 = red[9]  * inv - red[2] * red[3] * minv;
    float S21 = red[10] * inv - red[2] * red[4] * minv;
    float S30 = red[11] * inv - red[3] * red[3] * minv;
    float S31 = red[12] * inv - red[3] * red[4] * minv;
    float S40 = S31;
    float S41 = red[13] * inv - red[4] * red[4] * minv;
    float p00 = S30 + diag0, p01 = S31, p10 = S40, p11 = S41 + diag1;
    float rdet = 1.0f / (p00 * p11 - p01 * p10);
    float Ka0 = (p11 * S00 - p01 * S01) * rdet, Kb0 = (p00 * S01 - p10 * S00) * rdet;
    float Ka1 = (p11 * S10 - p01 * S11) * rdet, Kb1 = (p00 * S11 - p10 * S10) * rdet;
    float Ka2 = (p11 * S20 - p01 * S21) * rdet, Kb2 = (p00 * S21 - p10 * S20) * rdet;
    float Ka3 = (p11 * S30 - p01 * S31) * rdet, Kb3 = (p00 * S31 - p10 * S30) * rdet;
    float Ka4 = (p11 * S40 - p01 * S41) * rdet, Kb4 = (p00 * S41 - p10 * S40) * rdet;

    // ---- Kalman update + direct stores (2 owned particles) ----
    #pragma unroll
    for (int mm = 0; mm < 2; ++mm) {
        const int p = c + 32 * (2 * h + mm);
        const float2 yy = *(const float2*)(y_obs + (b * 128 + (size_t)p) * 2);
        float i0 = yy.x - xpo[mm][3];
        float i1 = yy.y - xpo[mm][4];
        float* o = out + (b * 128 + (size_t)p) * 5;
        o[0] = xpo[mm][0] + i0 * Ka0 + i1 * Kb0;
        o[1] = xpo[mm][1] + i0 * Ka1 + i1 * Kb1;
        o[2] = xpo[mm][2] + i0 * Ka2 + i1 * Kb2;
        o[3] = xpo[mm][3] + i0 * Ka3 + i1 * Kb3;
        o[4] = xpo[mm][4] + i0 * Ka4 + i1 * Kb4;
    }
}

extern "C" void kernel_launch(void* const* d_in, const int* in_sizes, int n_in,
                              void* d_out, int out_size, void* d_ws, size_t ws_size,
                              hipStream_t stream) {
    const float* state_old = (const float*)d_in[0];
    const float* y_obs     = (const float*)d_in[1];
    const float* encoding  = (const float*)d_in[2];
    const float* pw1 = (const float*)d_in[3];
    const float* pb1 = (const float*)d_in[4];
    const float* pw2 = (const float*)d_in[5];
    const float* pb2 = (const float*)d_in[6];
    const float* pw3 = (const float*)d_in[7];
    const float* pb3 = (const float*)d_in[8];
    const float* nw1 = (const float*)d_in[9];
    const float* nb1 = (const float*)d_in[10];
    const float* nw2 = (const float*)d_in[11];
    const float* nb2 = (const float*)d_in[12];
    const float* lob = (const float*)d_in[13];
    const float* fob = (const float*)d_in[14];
    float* out = (float*)d_out;

    const int B = 16384;
    dim3 grid(B / NBPB);
    dim3 block(256);
    hipLaunchKernelGGL(ekf_fused, grid, block, 0, stream,
                       state_old, y_obs, encoding,
                       pw1, pb1, pw2, pb2, pw3, pb3,
                       nw1, nb1, nw2, nb2, lob, fob, out);
}

// Round 20
// 59.054 us; speedup vs baseline: 1.5376x; 1.5376x over previous
//
#include <hip/hip_runtime.h>

// EKF_v2: B=16384, N=128, DX=5, DZ=2.
// R18 (VALU+LDS-table, PASSED 61.1us) + ONE change: weight table packed to
// cut DS-pipe ops 7/j -> 3/j. Diagnosis: DS cyc/wave ~2800 x 64 waves/CU
// = 75us = observed dur; table reads are 75% of it. pw2 stored as bf16
// pairs (8 u32 = 2 ds_read_b128) + one float4 {pb2 f32, pw3j0, pw3j1, pad}.
// Unpack = mask/shl (exact bf16->f32), VALU has headroom. Same k-order.
// bf16 layer-2 weights match the R13 MFMA path's precision (0.031 passed).
// R19's SMEM attempt reverted (s_load latency serialization, 90us).

#define NBPB 4  // batches (=waves) per block

typedef float v2f __attribute__((ext_vector_type(2)));
__device__ __forceinline__ v2f spl(float x) { v2f r; r.x = x; r.y = x; return r; }
__device__ __forceinline__ float hi16f(unsigned int u) {
    return __builtin_bit_cast(float, u & 0xffff0000u);
}
__device__ __forceinline__ float lo16f(unsigned int u) {
    return __builtin_bit_cast(float, u << 16);
}

__global__ __launch_bounds__(256) void ekf_fused(
    const float* __restrict__ state_old,  // (B,128,5)
    const float* __restrict__ y_obs,      // (B,128,2)
    const float* __restrict__ encoding,   // (B,128)
    const float* __restrict__ pw1,        // (2,16)
    const float* __restrict__ pb1,        // (16)
    const float* __restrict__ pw2,        // (16,32)
    const float* __restrict__ pb2,        // (32)
    const float* __restrict__ pw3,        // (32,2)
    const float* __restrict__ pb3,        // (2)
    const float* __restrict__ nw1,        // (128,32)
    const float* __restrict__ nb1,        // (32)
    const float* __restrict__ nw2,        // (32,2)
    const float* __restrict__ nb2,        // (2)
    const float* __restrict__ lob,        // (2)
    const float* __restrict__ fob,        // (2)
    float* __restrict__ out)              // (B,128,5)
{
    __shared__ __align__(16) float s_state[NBPB * 640];
    // s_wt[j*12 + r] (u32): r<8 -> bf16 pair (hi=pw2[2r][j], lo=pw2[2r+1][j]);
    // r=8 -> pb2[j] (f32 bits); r=9,10 -> pw3[j][0..1] (f32); r=11 pad.
    // stride 48B -> every j 16B-aligned.
    __shared__ __align__(16) unsigned int s_wt[32 * 12];

    const int t = threadIdx.x;
    const int base = blockIdx.x * NBPB;

    // ---- stage state (coalesced float4) + packed weight table ----
    {
        const float4* src = (const float4*)(state_old + (size_t)base * 640);
        float4* dst = (float4*)s_state;
        #pragma unroll
        for (int i = t; i < NBPB * 160; i += 256) dst[i] = src[i];
        for (int idx = t; idx < 384; idx += 256) {
            int j = idx / 12, r = idx % 12;
            unsigned int u;
            if (r < 8) {
                unsigned short ha = __builtin_bit_cast(unsigned short, (__bf16)pw2[(2 * r) * 32 + j]);
                unsigned short hb = __builtin_bit_cast(unsigned short, (__bf16)pw2[(2 * r + 1) * 32 + j]);
                u = ((unsigned int)ha << 16) | (unsigned int)hb;
            } else if (r == 8)  u = __builtin_bit_cast(unsigned int, pb2[j]);
            else if (r == 9)    u = __builtin_bit_cast(unsigned int, pw3[2 * j]);
            else if (r == 10)   u = __builtin_bit_cast(unsigned int, pw3[2 * j + 1]);
            else                u = 0u;
            s_wt[idx] = u;
        }
    }
    __syncthreads();

    const int w = t >> 6;    // wave = batch within block
    const int l = t & 63;
    const int c = l & 31;    // particle column
    const int h = l >> 5;    // lane half -> k-split & particle ownership
    const size_t b = (size_t)base + w;

    // ---- noise MLP: j = c, k-range split across halves ----
    float diag0, diag1;
    {
        const float4* eg4 = (const float4*)(encoding + b * 128) + h * 16;
        const float* wp = nw1 + (size_t)(h * 64) * 32 + c;
        float a0 = 0.f, a1 = 0.f, a2 = 0.f, a3 = 0.f;
        #pragma unroll
        for (int kk = 0; kk < 16; ++kk) {
            float4 e4 = eg4[kk];
            a0 = fmaf(e4.x, wp[(4 * kk + 0) * 32], a0);
            a1 = fmaf(e4.y, wp[(4 * kk + 1) * 32], a1);
            a2 = fmaf(e4.z, wp[(4 * kk + 2) * 32], a2);
            a3 = fmaf(e4.w, wp[(4 * kk + 3) * 32], a3);
        }
        float acc = (a0 + a1) + (a2 + a3);
        acc += __shfl_xor(acc, 32, 64);   // combine k-halves
        acc += nb1[c];
        float hh = fmaxf(acc, 0.f);
        float d0 = hh * nw2[2 * c + 0];
        float d1 = hh * nw2[2 * c + 1];
        #pragma unroll
        for (int off = 1; off < 32; off <<= 1) {
            d0 += __shfl_xor(d0, off, 64);
            d1 += __shfl_xor(d1, off, 64);
        }
        float e0 = d0 + nb2[0] + lob[0];
        float e1 = d1 + nb2[1] + lob[1];
        diag0 = fmaf(e0, e0, fob[0]);
        diag1 = fmaf(e1, e1, fob[1]);
    }

    const float* sp = s_state + w * 640;
    const int p0 = c + 32 * (2 * h);
    const int p1 = c + 32 * (2 * h + 1);

    // ---- process model pose for the 2 owned particles ----
    float xpo[2][5];
    float va, tda, vb, tdb;
    {
        const float* s5a = sp + p0 * 5;
        const float* s5b = sp + p1 * 5;
        va = s5a[3]; tda = s5a[4];
        vb = s5b[3]; tdb = s5b[4];
        float tha = s5a[2] + tda;
        float thb = s5b[2] + tdb;
        xpo[0][0] = fmaf(va, __sinf(tha), s5a[0]);
        xpo[0][1] = fmaf(va, __cosf(tha), s5a[1]);
        xpo[0][2] = tha;
        xpo[1][0] = fmaf(vb, __sinf(thb), s5b[0]);
        xpo[1][1] = fmaf(vb, __cosf(thb), s5b[1]);
        xpo[1][2] = thb;
    }

    // ---- layer-1 packed: h1p[q] = (h1a[q], h1b[q]); pw1/pb1 via s_load ----
    v2f h1p[16];
    {
        v2f vv;  vv.x = va;  vv.y = vb;
        v2f tdv; tdv.x = tda; tdv.y = tdb;
        #pragma unroll
        for (int q = 0; q < 16; ++q) {
            v2f tmp = __builtin_elementwise_fma(tdv, spl(pw1[16 + q]), spl(pb1[q]));
            v2f hq  = __builtin_elementwise_fma(vv, spl(pw1[q]), tmp);
            h1p[q] = __builtin_elementwise_max(hq, spl(0.0f));
        }
    }

    // ---- layers 2+3: 3 DS reads/j (2x uint4 + 1x float4), bf16 unpack ----
    v2f o3p = spl(0.0f), o4p = spl(0.0f);
    #pragma unroll 2
    for (int j = 0; j < 32; ++j) {
        const unsigned int* wj = s_wt + j * 12;
        uint4 u0 = *(const uint4*)(wj);
        uint4 u1 = *(const uint4*)(wj + 4);
        float4 tail = *(const float4*)(wj + 8); // {pb2, pw30, pw31, pad}
        v2f acc = spl(tail.x);
        acc = __builtin_elementwise_fma(h1p[0],  spl(hi16f(u0.x)), acc);
        acc = __builtin_elementwise_fma(h1p[1],  spl(lo16f(u0.x)), acc);
        acc = __builtin_elementwise_fma(h1p[2],  spl(hi16f(u0.y)), acc);
        acc = __builtin_elementwise_fma(h1p[3],  spl(lo16f(u0.y)), acc);
        acc = __builtin_elementwise_fma(h1p[4],  spl(hi16f(u0.z)), acc);
        acc = __builtin_elementwise_fma(h1p[5],  spl(lo16f(u0.z)), acc);
        acc = __builtin_elementwise_fma(h1p[6],  spl(hi16f(u0.w)), acc);
        acc = __builtin_elementwise_fma(h1p[7],  spl(lo16f(u0.w)), acc);
        acc = __builtin_elementwise_fma(h1p[8],  spl(hi16f(u1.x)), acc);
        acc = __builtin_elementwise_fma(h1p[9],  spl(lo16f(u1.x)), acc);
        acc = __builtin_elementwise_fma(h1p[10], spl(hi16f(u1.y)), acc);
        acc = __builtin_elementwise_fma(h1p[11], spl(lo16f(u1.y)), acc);
        acc = __builtin_elementwise_fma(h1p[12], spl(hi16f(u1.z)), acc);
        acc = __builtin_elementwise_fma(h1p[13], spl(lo16f(u1.z)), acc);
        acc = __builtin_elementwise_fma(h1p[14], spl(hi16f(u1.w)), acc);
        acc = __builtin_elementwise_fma(h1p[15], spl(lo16f(u1.w)), acc);
        v2f r = __builtin_elementwise_max(acc, spl(0.0f));
        o3p = __builtin_elementwise_fma(r, spl(tail.y), o3p);
        o4p = __builtin_elementwise_fma(r, spl(tail.z), o4p);
    }
    {
        float pb30 = pb3[0], pb31 = pb3[1];
        xpo[0][3] = va + o3p.x + pb30;
        xpo[0][4] = tda + o4p.x + pb31;
        xpo[1][3] = vb + o3p.y + pb30;
        xpo[1][4] = tdb + o4p.y + pb31;
    }

    // ---- raw moments: ONE butterfly phase (6 levels), 14 chains ----
    float red[14];
    #pragma unroll
    for (int i = 0; i < 5; ++i) red[i] = xpo[0][i] + xpo[1][i];
    red[5]  = xpo[0][0] * xpo[0][3] + xpo[1][0] * xpo[1][3];
    red[6]  = xpo[0][0] * xpo[0][4] + xpo[1][0] * xpo[1][4];
    red[7]  = xpo[0][1] * xpo[0][3] + xpo[1][1] * xpo[1][3];
    red[8]  = xpo[0][1] * xpo[0][4] + xpo[1][1] * xpo[1][4];
    red[9]  = xpo[0][2] * xpo[0][3] + xpo[1][2] * xpo[1][3];
    red[10] = xpo[0][2] * xpo[0][4] + xpo[1][2] * xpo[1][4];
    red[11] = xpo[0][3] * xpo[0][3] + xpo[1][3] * xpo[1][3];
    red[12] = xpo[0][3] * xpo[0][4] + xpo[1][3] * xpo[1][4];
    red[13] = xpo[0][4] * xpo[0][4] + xpo[1][4] * xpo[1][4];
    #pragma unroll
    for (int off = 1; off < 64; off <<= 1) {
        #pragma unroll
        for (int r = 0; r < 14; ++r)
            red[r] += __shfl_xor(red[r], off, 64);
    }

    // ---- covariances + analytic 2x2 solve ----
    const float inv  = 1.0f / 127.0f;
    const float minv = inv * 0.0078125f; // 1/(127*128)
    float S00 = red[5]  * inv - red[0] * red[3] * minv;
    float S01 = red[6]  * inv - red[0] * red[4] * minv;
    float S10 = red[7]  * inv - red[1] * red[3] * minv;
    float S11 = red[8]  * inv - red[1] * red[4] * minv;
    float S20 = red[9]  * inv - red[2] * red[3] * minv;
    float S21 = red[10] * inv - red[2] * red[4] * minv;
    float S30 = red[11] * inv - red[3] * red[3] * minv;
    float S31 = red[12] * inv - red[3] * red[4] * minv;
    float S40 = S31;
    float S41 = red[13] * inv - red[4] * red[4] * minv;
    float p00 = S30 + diag0, p01 = S31, p10 = S40, p11 = S41 + diag1;
    float rdet = 1.0f / (p00 * p11 - p01 * p10);
    float Ka0 = (p11 * S00 - p01 * S01) * rdet, Kb0 = (p00 * S01 - p10 * S00) * rdet;
    float Ka1 = (p11 * S10 - p01 * S11) * rdet, Kb1 = (p00 * S11 - p10 * S10) * rdet;
    float Ka2 = (p11 * S20 - p01 * S21) * rdet, Kb2 = (p00 * S21 - p10 * S20) * rdet;
    float Ka3 = (p11 * S30 - p01 * S31) * rdet, Kb3 = (p00 * S31 - p10 * S30) * rdet;
    float Ka4 = (p11 * S40 - p01 * S41) * rdet, Kb4 = (p00 * S41 - p10 * S40) * rdet;

    // ---- Kalman update + direct stores (2 owned particles) ----
    #pragma unroll
    for (int mm = 0; mm < 2; ++mm) {
        const int p = c + 32 * (2 * h + mm);
        const float2 yy = *(const float2*)(y_obs + (b * 128 + (size_t)p) * 2);
        float i0 = yy.x - xpo[mm][3];
        float i1 = yy.y - xpo[mm][4];
        float* o = out + (b * 128 + (size_t)p) * 5;
        o[0] = xpo[mm][0] + i0 * Ka0 + i1 * Kb0;
        o[1] = xpo[mm][1] + i0 * Ka1 + i1 * Kb1;
        o[2] = xpo[mm][2] + i0 * Ka2 + i1 * Kb2;
        o[3] = xpo[mm][3] + i0 * Ka3 + i1 * Kb3;
        o[4] = xpo[mm][4] + i0 * Ka4 + i1 * Kb4;
    }
}

extern "C" void kernel_launch(void* const* d_in, const int* in_sizes, int n_in,
                              void* d_out, int out_size, void* d_ws, size_t ws_size,
                              hipStream_t stream) {
    const float* state_old = (const float*)d_in[0];
    const float* y_obs     = (const float*)d_in[1];
    const float* encoding  = (const float*)d_in[2];
    const float* pw1 = (const float*)d_in[3];
    const float* pb1 = (const float*)d_in[4];
    const float* pw2 = (const float*)d_in[5];
    const float* pb2 = (const float*)d_in[6];
    const float* pw3 = (const float*)d_in[7];
    const float* pb3 = (const float*)d_in[8];
    const float* nw1 = (const float*)d_in[9];
    const float* nb1 = (const float*)d_in[10];
    const float* nw2 = (const float*)d_in[11];
    const float* nb2 = (const float*)d_in[12];
    const float* lob = (const float*)d_in[13];
    const float* fob = (const float*)d_in[14];
    float* out = (float*)d_out;

    const int B = 16384;
    dim3 grid(B / NBPB);
    dim3 block(256);
    hipLaunchKernelGGL(ekf_fused, grid, block, 0, stream,
                       state_old, y_obs, encoding,
                       pw1, pb1, pw2, pb2, pw3, pb3,
                       nw1, nb1, nw2, nb2, lob, fob, out);
}